// Round 2
// baseline (993.513 us; speedup 1.0000x reference)
//
#include <hip/hip_runtime.h>
#include <math.h>

// MultiHeadAttention: B=2, S=2048, D=1024, H=16, Dh=64, fp32 in/out.
// Round 1: fp32 vector-ALU pipeline (no fp32 MFMA on CDNA4).
//   k1: QKV projection GEMM, 128x128 tile, 8x8 micro-tile, permuted store [B,H,S,Dh]
//   k2: causal flash attention, 64x64 tiles, online softmax
//   k3: output projection GEMM (same structure), plain store
// Workspace: q,k,v,ctx = 4 x 16.78 MB = 67.1 MB fp32.

#define H_  16
#define DH_ 64
#define D_  1024
#define S_  2048
#define B_  2

// ---------------------------------------------------------------------------
// GEMM: out = A[4096,1024] @ W[1024,1024] + bias
// 256 threads, BM=BN=128, BK=16, 8x8 micro-tile per thread (4+4 split rows/cols).
// A-tile k-major As[k][m] (pitch 132 floats: 16B-aligned rows, 2-way-free banks),
// W-tile row-major Bs[k][n] (pitch 132), both read as ds_read_b128.
// QKV=1: store permuted to [B,H,S,Dh]; 128-col tile covers heads {2*jt, 2*jt+1}.
// ---------------------------------------------------------------------------
template<int QKV>
__global__ __launch_bounds__(256) void gemm_k(
    const float* __restrict__ A,
    const float* __restrict__ W0, const float* __restrict__ W1, const float* __restrict__ W2,
    const float* __restrict__ b0, const float* __restrict__ b1, const float* __restrict__ b2,
    float* __restrict__ o0, float* __restrict__ o1, float* __restrict__ o2)
{
    const float* W = W0; const float* bias = b0; float* out = o0;
    if (QKV) {
        if (blockIdx.z == 1)      { W = W1; bias = b1; out = o1; }
        else if (blockIdx.z == 2) { W = W2; bias = b2; out = o2; }
    }
    const int mt = blockIdx.x;            // token tile (128 rows)
    const int jt = blockIdx.y;            // out-col tile (128 cols)
    const int tid = threadIdx.x;
    const int tx = tid & 15, ty = tid >> 4;
    const int r0 = ty * 4, c0 = tx * 4;   // quadrant origins; +64 for second half
    const int n0 = mt * 128, j0 = jt * 128;

    __shared__ float As[16][132];   // As[k][m]
    __shared__ float Bs[16][132];   // Bs[k][n]

    // A staging: 128 rows x 16 k-cols; 2 lanes per row, 8 floats per lane.
    const int ar = tid >> 1;              // 0..127
    const int ac = (tid & 1) * 8;         // 0 or 8
    // W staging: 16 k-rows x 128 cols; 16 lanes per row, 8 floats per lane.
    const int wr = tid >> 4;              // 0..15
    const int wc = (tid & 15) * 8;        // 0..120

    float acc[8][8] = {};

    for (int k0 = 0; k0 < D_; k0 += 16) {
        float4 a0 = *(const float4*)&A[(size_t)(n0 + ar) * D_ + k0 + ac];
        float4 a1 = *(const float4*)&A[(size_t)(n0 + ar) * D_ + k0 + ac + 4];
        float4 w0 = *(const float4*)&W[(size_t)(k0 + wr) * D_ + j0 + wc];
        float4 w1 = *(const float4*)&W[(size_t)(k0 + wr) * D_ + j0 + wc + 4];
        __syncthreads();                  // previous iteration's LDS reads done
        As[ac + 0][ar] = a0.x; As[ac + 1][ar] = a0.y;
        As[ac + 2][ar] = a0.z; As[ac + 3][ar] = a0.w;
        As[ac + 4][ar] = a1.x; As[ac + 5][ar] = a1.y;
        As[ac + 6][ar] = a1.z; As[ac + 7][ar] = a1.w;
        *(float4*)&Bs[wr][wc]     = w0;
        *(float4*)&Bs[wr][wc + 4] = w1;
        __syncthreads();
        #pragma unroll
        for (int kk = 0; kk < 16; ++kk) {
            float4 a4l = *(const float4*)&As[kk][r0];
            float4 a4h = *(const float4*)&As[kk][r0 + 64];
            float4 b4l = *(const float4*)&Bs[kk][c0];
            float4 b4h = *(const float4*)&Bs[kk][c0 + 64];
            float av[8] = {a4l.x, a4l.y, a4l.z, a4l.w, a4h.x, a4h.y, a4h.z, a4h.w};
            float bv[8] = {b4l.x, b4l.y, b4l.z, b4l.w, b4h.x, b4h.y, b4h.z, b4h.w};
            #pragma unroll
            for (int i = 0; i < 8; ++i)
                #pragma unroll
                for (int j = 0; j < 8; ++j)
                    acc[i][j] = fmaf(av[i], bv[j], acc[i][j]);
        }
    }

    float4 bbl = *(const float4*)&bias[j0 + c0];
    float4 bbh = *(const float4*)&bias[j0 + c0 + 64];
    float bvv[8] = {bbl.x, bbl.y, bbl.z, bbl.w, bbh.x, bbh.y, bbh.z, bbh.w};

    #pragma unroll
    for (int ih = 0; ih < 2; ++ih) {
        #pragma unroll
        for (int i = 0; i < 4; ++i) {
            int n = n0 + r0 + ih * 64 + i;
            #pragma unroll
            for (int jh = 0; jh < 2; ++jh) {
                float4 ov;
                ov.x = acc[ih * 4 + i][jh * 4 + 0] + bvv[jh * 4 + 0];
                ov.y = acc[ih * 4 + i][jh * 4 + 1] + bvv[jh * 4 + 1];
                ov.z = acc[ih * 4 + i][jh * 4 + 2] + bvv[jh * 4 + 2];
                ov.w = acc[ih * 4 + i][jh * 4 + 3] + bvv[jh * 4 + 3];
                if (QKV) {
                    int b = n >> 11, s = n & (S_ - 1);
                    int head = jt * 2 + jh;             // 64-col quadrant == one head
                    *(float4*)&out[(((size_t)(b * H_ + head)) * S_ + s) * DH_ + c0] = ov;
                } else {
                    *(float4*)&out[(size_t)n * D_ + j0 + jh * 64 + c0] = ov;
                }
            }
        }
    }
}

// ---------------------------------------------------------------------------
// Causal flash attention. grid = (B*H, S/64), 256 threads.
// Per block: 64 Q rows, iterate K/V tiles kt=0..qt (causal skip).
// 4x4 micro-tiles for QK^T and P.V; P^T aliased into the dead K buffer so
// static LDS stays at 3*64*68*4 = 52224 B.
// Per-row softmax state (m,l) replicated across the 16 lanes of a row group.
// ---------------------------------------------------------------------------
__global__ __launch_bounds__(256) void attn_k(
    const float* __restrict__ q, const float* __restrict__ k,
    const float* __restrict__ v, float* __restrict__ ctx)
{
    const int bh = blockIdx.x;    // 0..31  (b*H + h)
    const int qt = blockIdx.y;    // 0..31  (q tile)
    const int tid = threadIdx.x;
    const int ty = tid >> 4, tx = tid & 15;
    const int r0 = ty * 4, c0 = tx * 4;

    __shared__ float Qs[64][68];
    __shared__ float KPs[64][68];   // K tile; overwritten with P^T after scores
    __shared__ float Vs[64][68];

    const float* qg = q + ((size_t)bh * S_ + qt * 64) * DH_;
    {
        int rr = tid >> 4;
        int cc = (tid & 15) * 4;
        #pragma unroll
        for (int p = 0; p < 4; ++p)
            *(float4*)&Qs[rr + 16 * p][cc] =
                *(const float4*)&qg[(size_t)(rr + 16 * p) * DH_ + cc];
    }

    float o[4][4] = {};
    float m[4], l[4];
    #pragma unroll
    for (int i = 0; i < 4; ++i) { m[i] = -INFINITY; l[i] = 0.f; }

    for (int kt = 0; kt <= qt; ++kt) {
        const float* kg = k + ((size_t)bh * S_ + kt * 64) * DH_;
        const float* vg = v + ((size_t)bh * S_ + kt * 64) * DH_;
        const int rr = tid >> 4;
        const int cc = (tid & 15) * 4;
        float4 kreg[4], vreg[4];
        #pragma unroll
        for (int p = 0; p < 4; ++p) {
            kreg[p] = *(const float4*)&kg[(size_t)(rr + 16 * p) * DH_ + cc];
            vreg[p] = *(const float4*)&vg[(size_t)(rr + 16 * p) * DH_ + cc];
        }
        __syncthreads();              // previous phase-C LDS reads done
        #pragma unroll
        for (int p = 0; p < 4; ++p) {
            *(float4*)&KPs[rr + 16 * p][cc] = kreg[p];
            *(float4*)&Vs[rr + 16 * p][cc]  = vreg[p];
        }
        __syncthreads();

        // ---- phase A: s[i][j] = Q[r0+i] . K[c0+j] ----
        float s[4][4] = {};
        #pragma unroll 4
        for (int d4 = 0; d4 < 16; ++d4) {
            float4 q4[4], k4[4];
            #pragma unroll
            for (int i = 0; i < 4; ++i) q4[i] = *(const float4*)&Qs[r0 + i][d4 * 4];
            #pragma unroll
            for (int j = 0; j < 4; ++j) k4[j] = *(const float4*)&KPs[c0 + j][d4 * 4];
            #pragma unroll
            for (int i = 0; i < 4; ++i) {
                #pragma unroll
                for (int j = 0; j < 4; ++j)
                    s[i][j] += q4[i].x * k4[j].x + q4[i].y * k4[j].y
                             + q4[i].z * k4[j].z + q4[i].w * k4[j].w;
            }
        }
        __syncthreads();              // all K reads done; KPs becomes P^T

        // ---- phase B: mask (before scale, as in reference), scale, online softmax ----
        #pragma unroll
        for (int i = 0; i < 4; ++i) {
            #pragma unroll
            for (int j = 0; j < 4; ++j) {
                if (kt == qt && (c0 + j) > (r0 + i)) s[i][j] = -INFINITY;
                else                                 s[i][j] *= 0.125f;  // 1/sqrt(64)
            }
            float tm = fmaxf(fmaxf(s[i][0], s[i][1]), fmaxf(s[i][2], s[i][3]));
            tm = fmaxf(tm, __shfl_xor(tm, 1));
            tm = fmaxf(tm, __shfl_xor(tm, 2));
            tm = fmaxf(tm, __shfl_xor(tm, 4));
            tm = fmaxf(tm, __shfl_xor(tm, 8));
            float mn = fmaxf(m[i], tm);          // finite from the first tile on
            float corr = __expf(m[i] - mn);      // exp(-inf)=0 on first tile
            float ps = 0.f;
            #pragma unroll
            for (int j = 0; j < 4; ++j) { s[i][j] = __expf(s[i][j] - mn); ps += s[i][j]; }
            ps += __shfl_xor(ps, 1);
            ps += __shfl_xor(ps, 2);
            ps += __shfl_xor(ps, 4);
            ps += __shfl_xor(ps, 8);
            l[i] = l[i] * corr + ps;
            m[i] = mn;
            #pragma unroll
            for (int j = 0; j < 4; ++j) o[i][j] *= corr;
            #pragma unroll
            for (int j = 0; j < 4; ++j) KPs[c0 + j][r0 + i] = s[i][j];  // P^T
        }
        __syncthreads();

        // ---- phase C: o[i][j] += sum_kk P[r0+i][kk] * V[kk][c0+j] ----
        #pragma unroll 4
        for (int kk = 0; kk < 64; ++kk) {
            float4 p4 = *(const float4*)&KPs[kk][r0];
            float4 v4 = *(const float4*)&Vs[kk][c0];
            float pa[4] = {p4.x, p4.y, p4.z, p4.w};
            float va[4] = {v4.x, v4.y, v4.z, v4.w};
            #pragma unroll
            for (int i = 0; i < 4; ++i) {
                #pragma unroll
                for (int j = 0; j < 4; ++j)
                    o[i][j] = fmaf(pa[i], va[j], o[i][j]);
            }
        }
    }

    // write ctx in [B,S,H*Dh] layout (ready for the output projection)
    const int b = bh >> 4, h = bh & (H_ - 1);
    #pragma unroll
    for (int i = 0; i < 4; ++i) {
        int srow = qt * 64 + r0 + i;
        float inv = 1.0f / l[i];
        float4 ov = { o[i][0] * inv, o[i][1] * inv, o[i][2] * inv, o[i][3] * inv };
        *(float4*)&ctx[((size_t)(b * S_ + srow)) * D_ + h * DH_ + c0] = ov;
    }
}

// ---------------------------------------------------------------------------
extern "C" void kernel_launch(void* const* d_in, const int* in_sizes, int n_in,
                              void* d_out, int out_size, void* d_ws, size_t ws_size,
                              hipStream_t stream)
{
    const float* x  = (const float*)d_in[0];
    const float* Wq = (const float*)d_in[1];
    const float* bq = (const float*)d_in[2];
    const float* Wk = (const float*)d_in[3];
    const float* bk = (const float*)d_in[4];
    const float* Wv = (const float*)d_in[5];
    const float* bv = (const float*)d_in[6];
    const float* Wo = (const float*)d_in[7];
    const float* bo = (const float*)d_in[8];
    float* out = (float*)d_out;

    const size_t per = (size_t)B_ * H_ * S_ * DH_;   // 4,194,304 floats
    float* qws = (float*)d_ws;
    float* kws = qws + per;
    float* vws = kws + per;
    float* cws = vws + per;   // total 67.1 MB fp32 workspace

    dim3 blk(256);
    dim3 g1(32, 8, 3);        // (4096/128 token tiles, 1024/128 col tiles, q/k/v)
    gemm_k<1><<<g1, blk, 0, stream>>>(x, Wq, Wk, Wv, bq, bk, bv, qws, kws, vws);

    dim3 g2(32, 32);          // (B*H, S/64)
    attn_k<<<g2, blk, 0, stream>>>(qws, kws, vws, cws);

    dim3 g3(32, 8, 1);
    gemm_k<0><<<g3, blk, 0, stream>>>(cws, Wo, nullptr, nullptr,
                                      bo, nullptr, nullptr,
                                      out, nullptr, nullptr);
}

// Round 3
// 478.586 us; speedup vs baseline: 2.0759x; 2.0759x over previous
//
#include <hip/hip_runtime.h>
#include <math.h>

// MultiHeadAttention: B=2, S=2048, D=1024, H=16, Dh=64, fp32 in/out.
// Round 2: bf16-MFMA projection GEMMs (m97-style 128x128 tile, global_load_lds,
//          T2 XOR-swizzled LDS), fp32 flash attention with bank-conflict fix +
//          descending-qt load balance; attn emits bf16 ctx for the out-proj.
// Workspace (67.11 MB, same as round 1):
//   [0..48M)   q,k,v fp32 [B,H,S,64]
//   [48..56M)  Xb bf16 [4096][1024]  (aliased as ctx bf16 after QKV GEMM)
//   [56..64M)  Wt bf16 4 x [1024 n][1024 k] (transposed weights)

#define H_  16
#define DH_ 64
#define D_  1024
#define S_  2048
#define B_  2

typedef __attribute__((ext_vector_type(8))) short short8;
typedef __attribute__((ext_vector_type(4))) float f32x4;

__device__ __forceinline__ unsigned short f2bf(float f) {
    union { float f; unsigned int u; } v; v.f = f;
    unsigned int r = (v.u + 0x7fffu + ((v.u >> 16) & 1u)) >> 16;   // RNE
    return (unsigned short)r;
}

__device__ __forceinline__ void gload_lds16(const void* g, void* l) {
    __builtin_amdgcn_global_load_lds(
        (const __attribute__((address_space(1))) void*)g,
        (__attribute__((address_space(3))) void*)l, 16, 0, 0);
}

// ---------------------------------------------------------------------------
// x fp32 [4096][1024] -> bf16 (as ushort). 8 elems/thread.
// ---------------------------------------------------------------------------
__global__ __launch_bounds__(256) void cvt_x_k(const float* __restrict__ x,
                                               unsigned short* __restrict__ xb)
{
    int i = (blockIdx.x * 256 + threadIdx.x) * 8;
    float4 a = *(const float4*)&x[i];
    float4 b = *(const float4*)&x[i + 4];
    uint4 o;
    o.x = f2bf(a.x) | ((unsigned)f2bf(a.y) << 16);
    o.y = f2bf(a.z) | ((unsigned)f2bf(a.w) << 16);
    o.z = f2bf(b.x) | ((unsigned)f2bf(b.y) << 16);
    o.w = f2bf(b.z) | ((unsigned)f2bf(b.w) << 16);
    *(uint4*)&xb[i] = o;
}

// ---------------------------------------------------------------------------
// W fp32 [k=1024][n=1024] -> Wt bf16 [n][k]. 64x64 LDS-tiled transpose.
// grid (16,16,4), z selects Wq/Wk/Wv/Wo.
// ---------------------------------------------------------------------------
__global__ __launch_bounds__(256) void tr_w_k(
    const float* __restrict__ W0, const float* __restrict__ W1,
    const float* __restrict__ W2, const float* __restrict__ W3,
    unsigned short* __restrict__ wt)
{
    const float* W = W0;
    if (blockIdx.z == 1) W = W1; else if (blockIdx.z == 2) W = W2;
    else if (blockIdx.z == 3) W = W3;
    unsigned short* out = wt + (size_t)blockIdx.z * 1048576;

    __shared__ float t[64][65];
    const int k0 = blockIdx.x * 64, n0 = blockIdx.y * 64;
    const int r = threadIdx.x >> 4, c4 = (threadIdx.x & 15) * 4;

    #pragma unroll
    for (int p = 0; p < 4; ++p) {
        float4 v = *(const float4*)&W[(size_t)(k0 + r + 16 * p) * D_ + n0 + c4];
        t[r + 16 * p][c4 + 0] = v.x; t[r + 16 * p][c4 + 1] = v.y;
        t[r + 16 * p][c4 + 2] = v.z; t[r + 16 * p][c4 + 3] = v.w;
    }
    __syncthreads();
    #pragma unroll
    for (int p = 0; p < 4; ++p) {
        int nn = r + 16 * p;
        uint2 o;
        o.x = f2bf(t[c4 + 0][nn]) | ((unsigned)f2bf(t[c4 + 1][nn]) << 16);
        o.y = f2bf(t[c4 + 2][nn]) | ((unsigned)f2bf(t[c4 + 3][nn]) << 16);
        *(uint2*)&out[(size_t)(n0 + nn) * D_ + k0 + c4] = o;
    }
}

// ---------------------------------------------------------------------------
// bf16 MFMA GEMM: out = A[4096,1024] @ W + bias (fp32 out).
// A = bf16 [row][k] (k-contig), W given as Wt bf16 [n][k] (k-contig).
// 256 thr = 4 waves (2x2 quadrants of a 128x128 tile), BK=64,
// mfma_f32_16x16x32_bf16, 4x4 fragments per wave.
// LDS 2x16KB, rows 128 B, 16B-slot XOR swizzle: phys_slot = slot ^ (row&7);
// staged via global_load_lds (linear dest) with inverse-swizzled global source.
// QKV=1: grid.z selects q/k/v, store permuted to [B,H,S,64] fp32.
// ---------------------------------------------------------------------------
template<int QKV>
__global__ __launch_bounds__(256) void gemm_bf16(
    const unsigned short* __restrict__ Ab,
    const unsigned short* __restrict__ Wt,
    const float* __restrict__ b0, const float* __restrict__ b1,
    const float* __restrict__ b2,
    float* __restrict__ o0, float* __restrict__ o1, float* __restrict__ o2)
{
    const unsigned short* W = Wt;
    const float* bias = b0;
    float* out = o0;
    if (QKV) {
        int z = blockIdx.z;
        W = Wt + (size_t)z * 1048576;
        if (z == 1)      { bias = b1; out = o1; }
        else if (z == 2) { bias = b2; out = o2; }
    }
    const int n0 = blockIdx.x * 128, j0 = blockIdx.y * 128;
    const int tid = threadIdx.x;
    const int lane = tid & 63, wq = tid >> 6;
    const int wm = wq >> 1, wn = wq & 1;          // wave quadrant (2x2)
    const int lr = lane & 15, lk = lane >> 4;     // frag row / k-block

    __shared__ __align__(16) char smem[32768];    // A: [0,16K), B: [16K,32K)

    f32x4 acc[4][4] = {};

    for (int k0 = 0; k0 < D_; k0 += 64) {
        __syncthreads();                          // previous LDS reads done
        #pragma unroll
        for (int c = 0; c < 4; ++c) {             // A tile: 128 rows x 64 bf16
            int u = c * 256 + tid;
            int r = u >> 3, sp = u & 7, sl = sp ^ (r & 7);
            gload_lds16(&Ab[(size_t)(n0 + r) * D_ + k0 + sl * 8], &smem[u * 16]);
        }
        #pragma unroll
        for (int c = 0; c < 4; ++c) {             // B tile: 128 n-rows x 64 bf16
            int u = c * 256 + tid;
            int r = u >> 3, sp = u & 7, sl = sp ^ (r & 7);
            gload_lds16(&W[(size_t)(j0 + r) * D_ + k0 + sl * 8],
                        &smem[16384 + u * 16]);
        }
        __syncthreads();                          // drains vmcnt(0)
        #pragma unroll
        for (int kc = 0; kc < 2; ++kc) {
            short8 a[4], b[4];
            #pragma unroll
            for (int m = 0; m < 4; ++m) {
                int row = wm * 64 + m * 16 + lr;
                int sp = (kc * 4 + lk) ^ (row & 7);
                a[m] = *(const short8*)&smem[row * 128 + sp * 16];
            }
            #pragma unroll
            for (int n = 0; n < 4; ++n) {
                int row = wn * 64 + n * 16 + lr;
                int sp = (kc * 4 + lk) ^ (row & 7);
                b[n] = *(const short8*)&smem[16384 + row * 128 + sp * 16];
            }
            #pragma unroll
            for (int m = 0; m < 4; ++m)
                #pragma unroll
                for (int n = 0; n < 4; ++n)
                    acc[m][n] = __builtin_amdgcn_mfma_f32_16x16x32_bf16(
                        a[m], b[n], acc[m][n], 0, 0, 0);
        }
    }

    // epilogue: C/D layout col = lane&15, row = (lane>>4)*4 + reg  [m89]
    float bn[4];
    #pragma unroll
    for (int n = 0; n < 4; ++n) bn[n] = bias[j0 + wn * 64 + n * 16 + lr];

    #pragma unroll
    for (int m = 0; m < 4; ++m) {
        #pragma unroll
        for (int n = 0; n < 4; ++n) {
            int col = j0 + wn * 64 + n * 16 + lr;
            #pragma unroll
            for (int r = 0; r < 4; ++r) {
                int row = n0 + wm * 64 + m * 16 + lk * 4 + r;
                float vv = acc[m][n][r] + bn[n];
                if (QKV) {
                    int bb = row >> 11, s = row & (S_ - 1);
                    int head = col >> 6, dh = col & 63;
                    out[(((size_t)(bb * H_ + head)) * S_ + s) * DH_ + dh] = vv;
                } else {
                    out[(size_t)row * D_ + col] = vv;
                }
            }
        }
    }
}

// ---------------------------------------------------------------------------
// Causal flash attention, fp32. grid = (B*H, S/64), 256 threads.
// Round-2 fixes: K columns remapped to tx+16j (conflict-free b128 reads),
// Pᵀ written as packed float4, descending-qt dispatch, bf16 ctx output.
// ---------------------------------------------------------------------------
__global__ __launch_bounds__(256) void attn_k(
    const float* __restrict__ q, const float* __restrict__ k,
    const float* __restrict__ v, unsigned short* __restrict__ ctx)
{
    const int bh = blockIdx.x;          // 0..31  (b*H + h)
    const int qt = 31 - blockIdx.y;     // descending work: heavy blocks first
    const int tid = threadIdx.x;
    const int ty = tid >> 4, tx = tid & 15;
    const int r0 = ty * 4;

    __shared__ float Qs[64][68];
    __shared__ float KPs[64][68];   // K tile; overwritten with Pᵀ after scores
    __shared__ float Vs[64][68];

    const float* qg = q + ((size_t)bh * S_ + qt * 64) * DH_;
    {
        int rr = tid >> 4, cc = (tid & 15) * 4;
        #pragma unroll
        for (int p = 0; p < 4; ++p)
            *(float4*)&Qs[rr + 16 * p][cc] =
                *(const float4*)&qg[(size_t)(rr + 16 * p) * DH_ + cc];
    }

    float o[4][4] = {};
    float m[4], l[4];
    #pragma unroll
    for (int i = 0; i < 4; ++i) { m[i] = -INFINITY; l[i] = 0.f; }

    for (int kt = 0; kt <= qt; ++kt) {
        const float* kg = k + ((size_t)bh * S_ + kt * 64) * DH_;
        const float* vg = v + ((size_t)bh * S_ + kt * 64) * DH_;
        const int rr = tid >> 4, cc = (tid & 15) * 4;
        float4 kreg[4], vreg[4];
        #pragma unroll
        for (int p = 0; p < 4; ++p) {
            kreg[p] = *(const float4*)&kg[(size_t)(rr + 16 * p) * DH_ + cc];
            vreg[p] = *(const float4*)&vg[(size_t)(rr + 16 * p) * DH_ + cc];
        }
        __syncthreads();              // previous phase-C LDS reads done
        #pragma unroll
        for (int p = 0; p < 4; ++p) {
            *(float4*)&KPs[rr + 16 * p][cc] = kreg[p];
            *(float4*)&Vs[rr + 16 * p][cc]  = vreg[p];
        }
        __syncthreads();

        // ---- phase A: s[i][j] = Q[r0+i] . K[tx+16j] (cols remapped) ----
        float s[4][4] = {};
        #pragma unroll 4
        for (int d4 = 0; d4 < 16; ++d4) {
            float4 q4[4], k4[4];
            #pragma unroll
            for (int i = 0; i < 4; ++i) q4[i] = *(const float4*)&Qs[r0 + i][d4 * 4];
            #pragma unroll
            for (int j = 0; j < 4; ++j) k4[j] = *(const float4*)&KPs[tx + 16 * j][d4 * 4];
            #pragma unroll
            for (int i = 0; i < 4; ++i) {
                #pragma unroll
                for (int j = 0; j < 4; ++j)
                    s[i][j] += q4[i].x * k4[j].x + q4[i].y * k4[j].y
                             + q4[i].z * k4[j].z + q4[i].w * k4[j].w;
            }
        }
        __syncthreads();              // all K reads done; KPs becomes Pᵀ

        // ---- phase B: mask before scale (as reference), online softmax ----
        #pragma unroll
        for (int i = 0; i < 4; ++i) {
            #pragma unroll
            for (int j = 0; j < 4; ++j) {
                if (kt == qt && (tx + 16 * j) > (r0 + i)) s[i][j] = -INFINITY;
                else                                      s[i][j] *= 0.125f;
            }
            float tm = fmaxf(fmaxf(s[i][0], s[i][1]), fmaxf(s[i][2], s[i][3]));
            tm = fmaxf(tm, __shfl_xor(tm, 1));
            tm = fmaxf(tm, __shfl_xor(tm, 2));
            tm = fmaxf(tm, __shfl_xor(tm, 4));
            tm = fmaxf(tm, __shfl_xor(tm, 8));
            float mn = fmaxf(m[i], tm);
            float corr = __expf(m[i] - mn);
            float ps = 0.f;
            #pragma unroll
            for (int j = 0; j < 4; ++j) { s[i][j] = __expf(s[i][j] - mn); ps += s[i][j]; }
            ps += __shfl_xor(ps, 1);
            ps += __shfl_xor(ps, 2);
            ps += __shfl_xor(ps, 4);
            ps += __shfl_xor(ps, 8);
            l[i] = l[i] * corr + ps;
            m[i] = mn;
            #pragma unroll
            for (int j = 0; j < 4; ++j) o[i][j] *= corr;
        }
        // Pᵀ write, packed float4 (bank-spread, BW-bound)
        #pragma unroll
        for (int j = 0; j < 4; ++j) {
            float4 pw = { s[0][j], s[1][j], s[2][j], s[3][j] };
            *(float4*)&KPs[tx + 16 * j][r0] = pw;
        }
        __syncthreads();

        // ---- phase C: o[i][j] += sum_kk P[r0+i][kk] * V[kk][4tx+j] ----
        #pragma unroll 4
        for (int kk = 0; kk < 64; ++kk) {
            float4 p4 = *(const float4*)&KPs[kk][r0];
            float4 v4 = *(const float4*)&Vs[kk][tx * 4];
            float pa[4] = {p4.x, p4.y, p4.z, p4.w};
            float va[4] = {v4.x, v4.y, v4.z, v4.w};
            #pragma unroll
            for (int i = 0; i < 4; ++i) {
                #pragma unroll
                for (int j = 0; j < 4; ++j)
                    o[i][j] = fmaf(pa[i], va[j], o[i][j]);
            }
        }
    }

    // ctx out as bf16 [B*S][1024] (k-contig for the out-proj A operand)
    const int bb = bh >> 4, hh = bh & (H_ - 1);
    #pragma unroll
    for (int i = 0; i < 4; ++i) {
        int srow = qt * 64 + r0 + i;
        float inv = 1.0f / l[i];
        uint2 pk;
        pk.x = f2bf(o[i][0] * inv) | ((unsigned)f2bf(o[i][1] * inv) << 16);
        pk.y = f2bf(o[i][2] * inv) | ((unsigned)f2bf(o[i][3] * inv) << 16);
        *(uint2*)&ctx[((size_t)(bb * S_ + srow)) * D_ + hh * DH_ + tx * 4] = pk;
    }
}

// ---------------------------------------------------------------------------
extern "C" void kernel_launch(void* const* d_in, const int* in_sizes, int n_in,
                              void* d_out, int out_size, void* d_ws, size_t ws_size,
                              hipStream_t stream)
{
    const float* x  = (const float*)d_in[0];
    const float* Wq = (const float*)d_in[1];
    const float* bq = (const float*)d_in[2];
    const float* Wk = (const float*)d_in[3];
    const float* bk = (const float*)d_in[4];
    const float* Wv = (const float*)d_in[5];
    const float* bv = (const float*)d_in[6];
    const float* Wo = (const float*)d_in[7];
    const float* bo = (const float*)d_in[8];
    float* out = (float*)d_out;

    const size_t per = (size_t)B_ * H_ * S_ * DH_;       // 4,194,304
    float* qws = (float*)d_ws;
    float* kws = qws + per;
    float* vws = kws + per;
    unsigned short* xb = (unsigned short*)(vws + per);   // bf16 x (8.39 MB)
    unsigned short* wt = xb + per;                       // 4 x 1M bf16 weights
    unsigned short* cb = xb;                             // ctx aliases Xb

    cvt_x_k<<<2048, 256, 0, stream>>>(x, xb);
    tr_w_k<<<dim3(16, 16, 4), 256, 0, stream>>>(Wq, Wk, Wv, Wo, wt);

    gemm_bf16<1><<<dim3(32, 8, 3), 256, 0, stream>>>(
        xb, wt, bq, bk, bv, qws, kws, vws);

    attn_k<<<dim3(32, 32), 256, 0, stream>>>(qws, kws, vws, cb);

    gemm_bf16<0><<<dim3(32, 8, 1), 256, 0, stream>>>(
        cb, wt + 3u * 1048576u, bo, nullptr, nullptr, out, nullptr, nullptr);
}

// Round 4
// 189.597 us; speedup vs baseline: 5.2401x; 2.5242x over previous
//
#include <hip/hip_runtime.h>
#include <math.h>

// MultiHeadAttention: B=2, S=2048, D=1024, H=16, Dh=64, fp32 in/out.
// Round 4: full bf16-MFMA pipeline.
//   k1: cvt x -> bf16;  k2: transpose W -> Wt bf16 [n][k]
//   k3: QKV GEMM (MFMA 128x128) -> Q,K bf16 [B,H,S,64], V bf16 [B,H,64,S]
//   k4: MFMA flash attention (swapped QK^T, lane-local softmax, P via LDS)
//   k5: out-proj GEMM (MFMA) -> fp32 out
// Workspace: qb,kb,vtb,xb (4 x 8.39 MB bf16) + wt (8.39 MB) = 41.9 MB.

#define H_  16
#define DH_ 64
#define D_  1024
#define S_  2048
#define B_  2

typedef __attribute__((ext_vector_type(8))) short short8;
typedef __attribute__((ext_vector_type(4))) float f32x4;

__device__ __forceinline__ unsigned short f2bf(float f) {
    union { float f; unsigned int u; } v; v.f = f;
    unsigned int r = (v.u + 0x7fffu + ((v.u >> 16) & 1u)) >> 16;   // RNE
    return (unsigned short)r;
}

__device__ __forceinline__ void gload_lds16(const void* g, void* l) {
    __builtin_amdgcn_global_load_lds(
        (const __attribute__((address_space(1))) void*)g,
        (__attribute__((address_space(3))) void*)l, 16, 0, 0);
}

// ---------------------------------------------------------------------------
// x fp32 [4096][1024] -> bf16. 8 elems/thread.
// ---------------------------------------------------------------------------
__global__ __launch_bounds__(256) void cvt_x_k(const float* __restrict__ x,
                                               unsigned short* __restrict__ xb)
{
    int i = (blockIdx.x * 256 + threadIdx.x) * 8;
    float4 a = *(const float4*)&x[i];
    float4 b = *(const float4*)&x[i + 4];
    uint4 o;
    o.x = f2bf(a.x) | ((unsigned)f2bf(a.y) << 16);
    o.y = f2bf(a.z) | ((unsigned)f2bf(a.w) << 16);
    o.z = f2bf(b.x) | ((unsigned)f2bf(b.y) << 16);
    o.w = f2bf(b.z) | ((unsigned)f2bf(b.w) << 16);
    *(uint4*)&xb[i] = o;
}

// ---------------------------------------------------------------------------
// W fp32 [k][n] -> Wt bf16 [n][k]. 64x64 LDS-tiled transpose. z: Wq/Wk/Wv/Wo.
// ---------------------------------------------------------------------------
__global__ __launch_bounds__(256) void tr_w_k(
    const float* __restrict__ W0, const float* __restrict__ W1,
    const float* __restrict__ W2, const float* __restrict__ W3,
    unsigned short* __restrict__ wt)
{
    const float* W = W0;
    if (blockIdx.z == 1) W = W1; else if (blockIdx.z == 2) W = W2;
    else if (blockIdx.z == 3) W = W3;
    unsigned short* out = wt + (size_t)blockIdx.z * 1048576;

    __shared__ float t[64][65];
    const int k0 = blockIdx.x * 64, n0 = blockIdx.y * 64;
    const int r = threadIdx.x >> 4, c4 = (threadIdx.x & 15) * 4;

    #pragma unroll
    for (int p = 0; p < 4; ++p) {
        float4 v = *(const float4*)&W[(size_t)(k0 + r + 16 * p) * D_ + n0 + c4];
        t[r + 16 * p][c4 + 0] = v.x; t[r + 16 * p][c4 + 1] = v.y;
        t[r + 16 * p][c4 + 2] = v.z; t[r + 16 * p][c4 + 3] = v.w;
    }
    __syncthreads();
    #pragma unroll
    for (int p = 0; p < 4; ++p) {
        int nn = r + 16 * p;
        uint2 o;
        o.x = f2bf(t[c4 + 0][nn]) | ((unsigned)f2bf(t[c4 + 1][nn]) << 16);
        o.y = f2bf(t[c4 + 2][nn]) | ((unsigned)f2bf(t[c4 + 3][nn]) << 16);
        *(uint2*)&out[(size_t)(n0 + nn) * D_ + k0 + c4] = o;
    }
}

// ---------------------------------------------------------------------------
// bf16 MFMA GEMM, 128x128 tile, BK=64, 4 waves (2x2), 4x4 frags.
// LDS XOR-slot swizzle, global_load_lds staging (inverse-swizzled source).
// QKV=1: z selects q/k/v; q,k stored bf16 [B,H,S,64]; v stored bf16 [B,H,64,S].
// QKV=0: fp32 row-major + bias.
// ---------------------------------------------------------------------------
template<int QKV>
__global__ __launch_bounds__(256) void gemm_bf16(
    const unsigned short* __restrict__ Ab,
    const unsigned short* __restrict__ Wt,
    const float* __restrict__ b0, const float* __restrict__ b1,
    const float* __restrict__ b2,
    void* __restrict__ o0, void* __restrict__ o1, void* __restrict__ o2)
{
    const unsigned short* W = Wt;
    const float* bias = b0;
    int z = 0;
    if (QKV) {
        z = blockIdx.z;
        W = Wt + (size_t)z * 1048576;
        if (z == 1) bias = b1; else if (z == 2) bias = b2;
    }
    const int n0 = blockIdx.x * 128, j0 = blockIdx.y * 128;
    const int tid = threadIdx.x;
    const int lane = tid & 63;
    const int wq = tid >> 6, wm = wq >> 1, wn = wq & 1;
    const int lr = lane & 15, lk = lane >> 4;

    __shared__ __align__(16) char smem[32768];

    f32x4 acc[4][4] = {};

    for (int k0 = 0; k0 < D_; k0 += 64) {
        __syncthreads();
        #pragma unroll
        for (int c = 0; c < 4; ++c) {
            int u = c * 256 + tid;
            int r = u >> 3, sp = u & 7, sl = sp ^ (r & 7);
            gload_lds16(&Ab[(size_t)(n0 + r) * D_ + k0 + sl * 8], &smem[u * 16]);
        }
        #pragma unroll
        for (int c = 0; c < 4; ++c) {
            int u = c * 256 + tid;
            int r = u >> 3, sp = u & 7, sl = sp ^ (r & 7);
            gload_lds16(&W[(size_t)(j0 + r) * D_ + k0 + sl * 8],
                        &smem[16384 + u * 16]);
        }
        __syncthreads();
        #pragma unroll
        for (int kc = 0; kc < 2; ++kc) {
            short8 a[4], b[4];
            #pragma unroll
            for (int m = 0; m < 4; ++m) {
                int row = wm * 64 + m * 16 + lr;
                int sp = (kc * 4 + lk) ^ (row & 7);
                a[m] = *(const short8*)&smem[row * 128 + sp * 16];
            }
            #pragma unroll
            for (int n = 0; n < 4; ++n) {
                int row = wn * 64 + n * 16 + lr;
                int sp = (kc * 4 + lk) ^ (row & 7);
                b[n] = *(const short8*)&smem[16384 + row * 128 + sp * 16];
            }
            #pragma unroll
            for (int m = 0; m < 4; ++m)
                #pragma unroll
                for (int n = 0; n < 4; ++n)
                    acc[m][n] = __builtin_amdgcn_mfma_f32_16x16x32_bf16(
                        a[m], b[n], acc[m][n], 0, 0, 0);
        }
    }

    float bn[4];
    #pragma unroll
    for (int n = 0; n < 4; ++n) bn[n] = bias[j0 + wn * 64 + n * 16 + lr];

    #pragma unroll
    for (int m = 0; m < 4; ++m) {
        #pragma unroll
        for (int n = 0; n < 4; ++n) {
            int col = j0 + wn * 64 + n * 16 + lr;
            int row0 = n0 + wm * 64 + m * 16 + lk * 4;
            if (QKV) {
                int head = col >> 6, dh = col & 63;
                int bb = row0 >> 11, s0 = row0 & (S_ - 1);
                float v0 = acc[m][n][0] + bn[n], v1 = acc[m][n][1] + bn[n];
                float v2 = acc[m][n][2] + bn[n], v3 = acc[m][n][3] + bn[n];
                if (z < 2) {            // Q,K -> [B,H,S,64]
                    unsigned short* out = (unsigned short*)(z == 0 ? o0 : o1);
                    size_t base = ((size_t)((bb << 4) + head) * S_) * 64 + dh;
                    out[base + (size_t)(s0 + 0) * 64] = f2bf(v0);
                    out[base + (size_t)(s0 + 1) * 64] = f2bf(v1);
                    out[base + (size_t)(s0 + 2) * 64] = f2bf(v2);
                    out[base + (size_t)(s0 + 3) * 64] = f2bf(v3);
                } else {                // V -> [B,H,64,S]
                    unsigned short* out = (unsigned short*)o2;
                    uint2 pk;
                    pk.x = f2bf(v0) | ((unsigned)f2bf(v1) << 16);
                    pk.y = f2bf(v2) | ((unsigned)f2bf(v3) << 16);
                    *(uint2*)&out[((size_t)((bb << 4) + head) * 64 + dh) * S_ + s0] = pk;
                }
            } else {
                float* out = (float*)o0;
                #pragma unroll
                for (int r = 0; r < 4; ++r)
                    out[(size_t)(row0 + r) * D_ + col] = acc[m][n][r] + bn[n];
            }
        }
    }
}

// ---------------------------------------------------------------------------
// MFMA flash attention. grid = (B*H, S/64), 256 thr = 4 waves x 16 q-rows.
// Swapped QK^T (mfma(K,Q)) -> scores lane-local per q-row (lx owns row lx):
// softmax = in-register reduce + 2 shfl_xor. P re-laid out via a per-wave
// 2 KB swizzled LDS tile; PV = mfma(P, V^T) with V staged from [B,H,64,S].
// K/V^T tiles: global_load_lds w16, XOR-slot swizzle (conflict-free b128).
// ---------------------------------------------------------------------------
__global__ __launch_bounds__(256) void attn_mfma(
    const unsigned short* __restrict__ q, const unsigned short* __restrict__ k,
    const unsigned short* __restrict__ vt, unsigned short* __restrict__ ctx)
{
    const int bh = blockIdx.x;          // b*H + h
    const int qt = 31 - blockIdx.y;     // heavy blocks first
    const int tid = threadIdx.x;
    const int lane = tid & 63, wq = tid >> 6;
    const int lx = lane & 15, hi = lane >> 4;

    // [0,8K) K tile  [8K,16K) V^T tile  [16K,24K) P tiles (2KB/wave)
    __shared__ __align__(16) char smem[24576];
    char* Pw = &smem[16384 + wq * 2048];

    // Q fragments (B-operand): lane holds Q[wq*16+lx][hi*8 + 32ks + 0..7]
    short8 qf[2];
    {
        const unsigned short* qrow =
            q + ((size_t)bh * S_ + qt * 64 + wq * 16 + lx) * 64;
        qf[0] = *(const short8*)&qrow[hi * 8];
        qf[1] = *(const short8*)&qrow[32 + hi * 8];
    }

    f32x4 o[4] = {};                    // O[hi*4+r][ct*16+lx]
    float m = -INFINITY, l = 0.f;       // state for q-row (wq*16+lx)
    const int qg = qt * 64 + wq * 16 + lx;

    for (int kt = 0; kt <= qt; ++kt) {
        __syncthreads();                // prev iter's K/V reads done
        #pragma unroll
        for (int c = 0; c < 2; ++c) {   // K tile: 64 rows x 128 B
            int u = c * 256 + tid;
            int r = u >> 3, sp = u & 7, sl = sp ^ (r & 7);
            gload_lds16(&k[((size_t)bh * S_ + kt * 64 + r) * 64 + sl * 8],
                        &smem[u * 16]);
        }
        #pragma unroll
        for (int c = 0; c < 2; ++c) {   // V^T tile: 64 d-rows x 128 B
            int u = c * 256 + tid;
            int r = u >> 3, sp = u & 7, sl = sp ^ (r & 7);
            gload_lds16(&vt[((size_t)bh * 64 + r) * S_ + kt * 64 + sl * 8],
                        &smem[8192 + u * 16]);
        }
        __syncthreads();                // vmcnt drained by barrier

        // ---- QK^T (swapped): s[rt] = S^T tile -> lane holds
        //      S[q=lx][kv = rt*16 + hi*4 + r] ----
        f32x4 s[4] = {};
        #pragma unroll
        for (int rt = 0; rt < 4; ++rt) {
            #pragma unroll
            for (int ks = 0; ks < 2; ++ks) {
                int row = rt * 16 + lx;
                int sp = (ks * 4 + hi) ^ (row & 7);
                short8 kf = *(const short8*)&smem[row * 128 + sp * 16];
                s[rt] = __builtin_amdgcn_mfma_f32_16x16x32_bf16(
                    kf, qf[ks], s[rt], 0, 0, 0);
            }
        }

        // ---- mask (before scale) + scale ----
        if (kt == qt) {
            #pragma unroll
            for (int rt = 0; rt < 4; ++rt)
                #pragma unroll
                for (int r = 0; r < 4; ++r) {
                    int kvg = kt * 64 + rt * 16 + hi * 4 + r;
                    s[rt][r] = (kvg > qg) ? -INFINITY : s[rt][r] * 0.125f;
                }
        } else {
            #pragma unroll
            for (int rt = 0; rt < 4; ++rt)
                #pragma unroll
                for (int r = 0; r < 4; ++r) s[rt][r] *= 0.125f;
        }

        // ---- online softmax, row = lx (partials across hi-groups) ----
        float tmax = s[0][0];
        #pragma unroll
        for (int rt = 0; rt < 4; ++rt) {
            tmax = fmaxf(tmax, fmaxf(fmaxf(s[rt][0], s[rt][1]),
                                     fmaxf(s[rt][2], s[rt][3])));
        }
        tmax = fmaxf(tmax, __shfl_xor(tmax, 16));
        tmax = fmaxf(tmax, __shfl_xor(tmax, 32));
        float mn = fmaxf(m, tmax);
        float corr = __expf(m - mn);
        float ps = 0.f;
        #pragma unroll
        for (int rt = 0; rt < 4; ++rt)
            #pragma unroll
            for (int r = 0; r < 4; ++r) {
                s[rt][r] = __expf(s[rt][r] - mn);
                ps += s[rt][r];
            }
        ps += __shfl_xor(ps, 16);
        ps += __shfl_xor(ps, 32);
        l = l * corr + ps;
        m = mn;

        // rescale O (rows hi*4+r; corr lives at lane hi*4+r)
        #pragma unroll
        for (int r = 0; r < 4; ++r) {
            float cr = __shfl(corr, hi * 4 + r);
            #pragma unroll
            for (int ct = 0; ct < 4; ++ct) o[ct][r] *= cr;
        }

        // ---- P -> bf16 -> per-wave swizzled LDS tile [16 q][64 kv] ----
        #pragma unroll
        for (int rt = 0; rt < 4; ++rt) {
            uint2 pk;
            pk.x = f2bf(s[rt][0]) | ((unsigned)f2bf(s[rt][1]) << 16);
            pk.y = f2bf(s[rt][2]) | ((unsigned)f2bf(s[rt][3]) << 16);
            int sl = 2 * rt + (hi >> 1);                 // 16B slot of 8B write
            *(uint2*)&Pw[lx * 128 + ((sl ^ (lx & 7)) * 16) + (hi & 1) * 8] = pk;
        }
        // A-frags: lane holds P[q=lx][32ks + 8hi + 0..7]
        short8 pf[2];
        #pragma unroll
        for (int ks = 0; ks < 2; ++ks) {
            int sl = ks * 4 + hi;
            pf[ks] = *(const short8*)&Pw[lx * 128 + ((sl ^ (lx & 7)) * 16)];
        }

        // ---- PV: O[q][d] += P . V^T ----
        #pragma unroll
        for (int ct = 0; ct < 4; ++ct) {
            #pragma unroll
            for (int ks = 0; ks < 2; ++ks) {
                int row = ct * 16 + lx;
                int sp = (ks * 4 + hi) ^ (row & 7);
                short8 vf = *(const short8*)&smem[8192 + row * 128 + sp * 16];
                o[ct] = __builtin_amdgcn_mfma_f32_16x16x32_bf16(
                    pf[ks], vf, o[ct], 0, 0, 0);
            }
        }
    }

    // ---- epilogue: ctx bf16 [B,S,D] ----
    const int b = bh >> 4, h = bh & (H_ - 1);
    #pragma unroll
    for (int r = 0; r < 4; ++r) {
        float inv = 1.0f / __shfl(l, hi * 4 + r);
        int srow = qt * 64 + wq * 16 + hi * 4 + r;
        #pragma unroll
        for (int ct = 0; ct < 4; ++ct)
            ctx[((size_t)(b * S_ + srow)) * D_ + h * 64 + ct * 16 + lx] =
                f2bf(o[ct][r] * inv);
    }
}

// ---------------------------------------------------------------------------
extern "C" void kernel_launch(void* const* d_in, const int* in_sizes, int n_in,
                              void* d_out, int out_size, void* d_ws, size_t ws_size,
                              hipStream_t stream)
{
    const float* x  = (const float*)d_in[0];
    const float* Wq = (const float*)d_in[1];
    const float* bq = (const float*)d_in[2];
    const float* Wk = (const float*)d_in[3];
    const float* bk = (const float*)d_in[4];
    const float* Wv = (const float*)d_in[5];
    const float* bv = (const float*)d_in[6];
    const float* Wo = (const float*)d_in[7];
    const float* bo = (const float*)d_in[8];
    float* out = (float*)d_out;

    const size_t per = (size_t)B_ * H_ * S_ * DH_;       // 4,194,304
    unsigned short* qb  = (unsigned short*)d_ws;
    unsigned short* kb  = qb + per;
    unsigned short* vtb = kb + per;
    unsigned short* xb  = vtb + per;
    unsigned short* wt  = xb + per;                      // 4 x 1M bf16
    unsigned short* cb  = xb;                            // ctx aliases xb

    cvt_x_k<<<2048, 256, 0, stream>>>(x, xb);
    tr_w_k<<<dim3(16, 16, 4), 256, 0, stream>>>(Wq, Wk, Wv, Wo, wt);

    gemm_bf16<1><<<dim3(32, 8, 3), 256, 0, stream>>>(
        xb, wt, bq, bk, bv, qb, kb, vtb);

    attn_mfma<<<dim3(32, 32), 256, 0, stream>>>(qb, kb, vtb, cb);

    gemm_bf16<0><<<dim3(32, 8, 1), 256, 0, stream>>>(
        cb, wt + 3u * 1048576u, bo, nullptr, nullptr, out, nullptr, nullptr);
}